// Round 7
// baseline (341.200 us; speedup 1.0000x reference)
//
#include <hip/hip_runtime.h>

#define M_VERT 32768
#define NBATCH 8
#define FIN 32
#define RANK 5
#define FILT 32
#define E_NNZ 262144
#define ROWLEN 256                    // NBATCH*FIN elements per vertex row
#define EVROW 40                      // fixed ev slots per row (P(cnt>40) ~ 1e-16)

typedef short short8 __attribute__((ext_vector_type(8)));
typedef float f32x4 __attribute__((ext_vector_type(4)));

__device__ __forceinline__ float bfl(unsigned int u) {           // low bf16 -> f32
    unsigned int x = u << 16; return __builtin_bit_cast(float, x);
}
__device__ __forceinline__ float bfh(unsigned int u) {           // high bf16 -> f32
    unsigned int x = u & 0xffff0000u; return __builtin_bit_cast(float, x);
}
__device__ __forceinline__ unsigned int f2bf(float f) {          // f32 -> bf16 (RNE)
    unsigned int x = __builtin_bit_cast(unsigned int, f);
    return (x + 0x7fffu + ((x >> 16) & 1u)) >> 16;
}
__device__ __forceinline__ unsigned int pk(float a, float b) {
    return f2bf(a) | (f2bf(b) << 16);
}

// ---------------- pack x -> T0 (slice-major [n][m][fin] bf16) + CSR build + packw ----------------
// T layout: addr(n,m,fin) = ((n*M + m)*32 + fin) ushorts; slice n = contiguous 2 MiB
// -> one batch-slice fits an XCD's 4 MiB L2 (the whole point of this layout).
// CSR: fixed-stride ev (EVROW slots/row), slot from the fill-cursor atomic (doubles
// as histogram) -- no prefix scan, no scatter dispatch (R6 win, kept).
// packw: first 640 threads pack W into the MFMA B-fragment layout.

__global__ void pack_kernel(const float* __restrict__ x, unsigned short* __restrict__ T0,
                            const int* __restrict__ rows, const int* __restrict__ cols,
                            const float* __restrict__ vals,
                            int* __restrict__ fill, int2* __restrict__ ev,
                            const float* __restrict__ W, unsigned short* __restrict__ Wb) {
    int tid = blockIdx.x * blockDim.x + threadIdx.x;   // M*32 threads
    int q = tid & 3;
    int m = (tid >> 2) & (M_VERT - 1);
    int n = tid >> 17;
    const float* src = x + ((size_t)n * M_VERT + m) * FIN + q * 8;
    float4 v0 = *(const float4*)(src);
    float4 v1 = *(const float4*)(src + 4);
    uint4 u;
    u.x = pk(v0.x, v0.y); u.y = pk(v0.z, v0.w);
    u.z = pk(v1.x, v1.y); u.w = pk(v1.z, v1.w);
    *(uint4*)(T0 + ((size_t)n * M_VERT + m) * 32 + q * 8) = u;

    if (tid < E_NNZ) {
        int rr = rows[tid];
        int pos = atomicAdd(&fill[rr], 1);
        if (pos < EVROW) {                       // safety clamp (never taken in practice)
            int2 p; p.x = cols[tid]; p.y = __builtin_bit_cast(int, vals[tid]);
            ev[rr * EVROW + pos] = p;
        }
    }

    if (tid < 640) {
        int lane = tid & 63;
        int kf = tid >> 6;
        int k = kf >> 1, ft = kf & 1;
        int f = ft * 16 + (lane & 15);
        int fin0 = (lane >> 4) * 8;
        unsigned short tmp[8];
#pragma unroll
        for (int j = 0; j < 8; ++j)
            tmp[j] = (unsigned short)f2bf(W[((fin0 + j) * RANK + k) * FILT + f]);
        uint4 uw;
        uw.x = (unsigned int)tmp[0] | ((unsigned int)tmp[1] << 16);
        uw.y = (unsigned int)tmp[2] | ((unsigned int)tmp[3] << 16);
        uw.z = (unsigned int)tmp[4] | ((unsigned int)tmp[5] << 16);
        uw.w = (unsigned int)tmp[6] | ((unsigned int)tmp[7] << 16);
        *(uint4*)(Wb + (size_t)tid * 8) = uw;
    }
}

// ---------------- SpMM (bf16), slice-major + XCD-affine, zero-reduce groups ----------------
// Tout[n] = (L*Tin)[n]  or  2*(L*Tin)[n] - Tsub[n], per contiguous 2 MiB slice n.
// blockIdx&7 = n pins slice n to one XCD (round-robin dispatch) -> the slice stays
// resident in that XCD's 4 MiB L2; random gathers become L2 hits (34.5 TB/s tier
// instead of the ~4.6 TB/s L3 tier that binds the interleaved-layout kernel).
// Economics fixes vs the R5 failure: block = 16 vertices x 16 lanes; group g owns
// vertex m0+g, lane lq owns uint lq of its 64 B slice-row -> k-dim is IN-lane, so
// NO shfl reduce, NO exec-masked epilogue; store is 256 B contiguous per wave.
// Each group loops its OWN true count (divergent loop: masked groups issue no
// memory ops -> no pad slots, no wave-max waste, no ev memset).
// ev pressure fix: rows staged once into LDS via nt loads (one-shot, off critical
// path -- unlike R3's fatal per-trip nt ev loads), so the 3 MB/XCD ev stream never
// touches L2 and the slice isn't evicted. Tsub nt (pure stream); Tout cached --
// slice n's lines land in XCD n's L2 and the NEXT spmm reads them on the same XCD.

__global__ __launch_bounds__(256) void spmm_kernel(const int* __restrict__ cnt,
                                                   const unsigned long long* __restrict__ ev,
                                                   const unsigned short* __restrict__ Tin,
                                                   const unsigned short* __restrict__ Tsub,
                                                   unsigned short* __restrict__ Tout, int cheb) {
    __shared__ unsigned long long sev[16 * EVROW];
    int n  = blockIdx.x & 7;                     // slice -> XCD
    int vb = blockIdx.x >> 3;                    // 0..2047
    int m0 = vb * 16;
    int t  = threadIdx.x;

    // stage 16 rows of ev (contiguous 5120 B, fixed stride) into LDS, nt
    const unsigned long long* eb = ev + (size_t)m0 * EVROW;
    for (int i = t; i < 16 * EVROW; i += 256)
        sev[i] = __builtin_nontemporal_load(eb + i);

    int g  = t >> 4;                             // vertex group 0..15
    int lq = t & 15;                             // uint lane within 64 B row
    int m  = m0 + g;
    int c  = cnt[m];
    if (c > EVROW) c = EVROW;                    // matches scatter clamp
    __syncthreads();

    const char* sb = (const char*)Tin + ((size_t)n << 21);   // slice base (2 MiB)
    unsigned int kof = (unsigned int)lq * 4u;
    const unsigned long long* evg = sev + g * EVROW;
    float a0 = 0.f, a1 = 0.f;
    for (int j = 0; j < c; ++j) {
        unsigned long long ed = evg[j];          // LDS broadcast within group
        unsigned int col = (unsigned int)ed;
        float v = __builtin_bit_cast(float, (unsigned int)(ed >> 32));
        unsigned int tv = *(const unsigned int*)(sb + (col << 6) + kof);
        a0 += v * bfl(tv);
        a1 += v * bfh(tv);
    }
    size_t moff = ((size_t)n << 21) + (((size_t)(unsigned int)m << 6) + kof);
    if (cheb) {
        unsigned int o = __builtin_nontemporal_load(
            (const unsigned int*)((const char*)Tsub + moff));
        a0 = 2.f * a0 - bfl(o);
        a1 = 2.f * a1 - bfh(o);
    }
    *(unsigned int*)((char*)Tout + moff) = pk(a0, a1);
}

// ---------------- final GEMM: out[n,m,f] = bias[f] + sum_k T_k[n][m][:] @ W_k ----------------
// MFMA 16x16x32 bf16; slice-major A -> each wave's A-read is 1 KB fully contiguous.
// grid = M/64 * 8 (n in low bits); out stores non-temporal (never re-read).

__global__ __launch_bounds__(256) void gemm_kernel(const unsigned short* __restrict__ T0,
                                                   const unsigned short* __restrict__ T1,
                                                   const unsigned short* __restrict__ T2,
                                                   const unsigned short* __restrict__ T3,
                                                   const unsigned short* __restrict__ T4,
                                                   const unsigned short* __restrict__ Wb,
                                                   const float* __restrict__ bias,
                                                   float* __restrict__ out) {
    int w = threadIdx.x >> 6;
    int l = threadIdx.x & 63;
    int n  = blockIdx.x & 7;
    int mb = blockIdx.x >> 3;
    int m0 = (mb * 4 + w) * 16;
    int lrow = l & 15;           // A's m-offset AND C's column f
    int quad = l >> 4;

    short8 bfrag[5][2];
#pragma unroll
    for (int kf = 0; kf < 10; ++kf)
        bfrag[kf >> 1][kf & 1] = *(const short8*)(Wb + ((size_t)kf * 64 + l) * 8);

    float b0 = bias[lrow];
    float b1 = bias[16 + lrow];

    const unsigned short* Ts[5] = {T0, T1, T2, T3, T4};
    size_t abase = ((size_t)n * M_VERT + (m0 + lrow)) * 32 + quad * 8;

    f32x4 c0 = {0.f, 0.f, 0.f, 0.f};
    f32x4 c1 = {0.f, 0.f, 0.f, 0.f};
#pragma unroll
    for (int k = 0; k < 5; ++k) {
        short8 a = *(const short8*)(Ts[k] + abase);
        c0 = __builtin_amdgcn_mfma_f32_16x16x32_bf16(a, bfrag[k][0], c0, 0, 0, 0);
        c1 = __builtin_amdgcn_mfma_f32_16x16x32_bf16(a, bfrag[k][1], c1, 0, 0, 0);
    }
    float* op = out + ((size_t)n * M_VERT + m0) * FILT;
#pragma unroll
    for (int r = 0; r < 4; ++r) {
        int orow = quad * 4 + r;
        __builtin_nontemporal_store(c0[r] + b0, &op[(size_t)orow * FILT + lrow]);
        __builtin_nontemporal_store(c1[r] + b1, &op[(size_t)orow * FILT + 16 + lrow]);
    }
}

// ---------------- launch ----------------

extern "C" void kernel_launch(void* const* d_in, const int* in_sizes, int n_in,
                              void* d_out, int out_size, void* d_ws, size_t ws_size,
                              hipStream_t stream) {
    const float* x    = (const float*)d_in[0];
    const float* vals = (const float*)d_in[1];
    const float* W    = (const float*)d_in[2];
    const float* bias = (const float*)d_in[3];
    const int*   rows = (const int*)d_in[4];
    const int*   cols = (const int*)d_in[5];
    float* out = (float*)d_out;

    // workspace: 5 bf16 T buffers (16 MiB each, slice-major) + fill + fixed-stride ev + Wb
    const size_t TSZ = (size_t)M_VERT * ROWLEN;
    unsigned short* T0 = (unsigned short*)d_ws;
    unsigned short* T1 = T0 + TSZ;
    unsigned short* T2 = T1 + TSZ;
    unsigned short* T3 = T2 + TSZ;
    unsigned short* T4 = T3 + TSZ;
    int*  fill = (int*)(T4 + TSZ);
    int2* ev   = (int2*)(fill + M_VERT);
    unsigned short* Wb = (unsigned short*)(ev + (size_t)M_VERT * EVROW);

    hipMemsetAsync(fill, 0, M_VERT * sizeof(int), stream);
    pack_kernel<<<M_VERT * 32 / 256, 256, 0, stream>>>(x, T0, rows, cols, vals,
                                                       fill, ev, W, Wb);

    // Chebyshev recurrence, all T_k kept (bf16); slice-major XCD-affine SpMM
    const unsigned long long* evq = (const unsigned long long*)ev;
    spmm_kernel<<<(M_VERT / 16) * 8, 256, 0, stream>>>(fill, evq, T0, T0, T1, 0);
    spmm_kernel<<<(M_VERT / 16) * 8, 256, 0, stream>>>(fill, evq, T1, T0, T2, 1);
    spmm_kernel<<<(M_VERT / 16) * 8, 256, 0, stream>>>(fill, evq, T2, T1, T3, 1);
    spmm_kernel<<<(M_VERT / 16) * 8, 256, 0, stream>>>(fill, evq, T3, T2, T4, 1);

    // single fused epilogue GEMM
    gemm_kernel<<<(M_VERT / 64) * 8, 256, 0, stream>>>(T0, T1, T2, T3, T4, Wb, bias, out);
}

// Round 8
// 250.926 us; speedup vs baseline: 1.3598x; 1.3598x over previous
//
#include <hip/hip_runtime.h>

#define M_VERT 32768
#define NBATCH 8
#define FIN 32
#define RANK 5
#define FILT 32
#define E_NNZ 262144
#define ROWLEN 256                    // NBATCH*FIN elements per vertex row
#define EVROW 40                      // fixed ev slots per row (P(cnt>40) ~ 1e-16), mult of 8

typedef short short8 __attribute__((ext_vector_type(8)));
typedef float f32x4 __attribute__((ext_vector_type(4)));

__device__ __forceinline__ float bfl(unsigned int u) {           // low bf16 -> f32
    unsigned int x = u << 16; return __builtin_bit_cast(float, x);
}
__device__ __forceinline__ float bfh(unsigned int u) {           // high bf16 -> f32
    unsigned int x = u & 0xffff0000u; return __builtin_bit_cast(float, x);
}
__device__ __forceinline__ unsigned int f2bf(float f) {          // f32 -> bf16 (RNE)
    unsigned int x = __builtin_bit_cast(unsigned int, f);
    return (x + 0x7fffu + ((x >> 16) & 1u)) >> 16;
}
__device__ __forceinline__ unsigned int pk(float a, float b) {
    return f2bf(a) | (f2bf(b) << 16);
}

// ---------------- pack x -> T0 (slice-major [n][m][fin] bf16) + CSR build + packw ----------------
// T layout: addr(n,m,fin) = ((n*M + m)*32 + fin) ushorts; slice n = contiguous 2 MiB
// -> one batch-slice fits an XCD's 4 MiB L2.
// CSR: fixed-stride ev (EVROW slots/row), slot from the fill-cursor atomic (doubles
// as histogram) -- no prefix scan, no scatter dispatch (R6 win, kept).
// packw: first 640 threads pack W into the MFMA B-fragment layout.

__global__ void pack_kernel(const float* __restrict__ x, unsigned short* __restrict__ T0,
                            const int* __restrict__ rows, const int* __restrict__ cols,
                            const float* __restrict__ vals,
                            int* __restrict__ fill, int2* __restrict__ ev,
                            const float* __restrict__ W, unsigned short* __restrict__ Wb) {
    int tid = blockIdx.x * blockDim.x + threadIdx.x;   // M*32 threads
    int q = tid & 3;
    int m = (tid >> 2) & (M_VERT - 1);
    int n = tid >> 17;
    const float* src = x + ((size_t)n * M_VERT + m) * FIN + q * 8;
    float4 v0 = *(const float4*)(src);
    float4 v1 = *(const float4*)(src + 4);
    uint4 u;
    u.x = pk(v0.x, v0.y); u.y = pk(v0.z, v0.w);
    u.z = pk(v1.x, v1.y); u.w = pk(v1.z, v1.w);
    *(uint4*)(T0 + ((size_t)n * M_VERT + m) * 32 + q * 8) = u;

    if (tid < E_NNZ) {
        int rr = rows[tid];
        int pos = atomicAdd(&fill[rr], 1);
        if (pos < EVROW) {                       // safety clamp (never taken in practice)
            int2 p; p.x = cols[tid]; p.y = __builtin_bit_cast(int, vals[tid]);
            ev[rr * EVROW + pos] = p;
        }
    }

    if (tid < 640) {
        int lane = tid & 63;
        int kf = tid >> 6;
        int k = kf >> 1, ft = kf & 1;
        int f = ft * 16 + (lane & 15);
        int fin0 = (lane >> 4) * 8;
        unsigned short tmp[8];
#pragma unroll
        for (int j = 0; j < 8; ++j)
            tmp[j] = (unsigned short)f2bf(W[((fin0 + j) * RANK + k) * FILT + f]);
        uint4 uw;
        uw.x = (unsigned int)tmp[0] | ((unsigned int)tmp[1] << 16);
        uw.y = (unsigned int)tmp[2] | ((unsigned int)tmp[3] << 16);
        uw.z = (unsigned int)tmp[4] | ((unsigned int)tmp[5] << 16);
        uw.w = (unsigned int)tmp[6] | ((unsigned int)tmp[7] << 16);
        *(uint4*)(Wb + (size_t)tid * 8) = uw;
    }
}

// ---------------- SpMM (bf16), slice-major + XCD-affine: traffic x economics x MLP ----------------
// Tout[n] = (L*Tin)[n]  or  2*(L*Tin)[n] - Tsub[n], per contiguous 2 MiB slice n.
// blockIdx&7 = n pins slice n to one XCD -> slice stays L2-resident (R5-proven:
// FETCH at compulsory). Block = 16 vertices x 16 lanes; group g owns vertex
// m0+g, lane lq owns uint lq of its 64 B slice-row -> k-dim in-lane, NO shfl
// reduce, NO exec-masked epilogue (R7-proven economics). Inner loop unrolled
// 8 edges/trip -> 8 outstanding 64 B gathers per group, 32 per wave (R0/R4-proven
// MLP; fixes R7's serial 1-gather chain). ev: DIRECT CACHED loads, group-uniform
// address -> broadcast (R5-proven; R7's LDS-nt staging was an 84 MB traffic
// own-goal, R3's per-trip nt was serialization). Rows 8-padded via ev memset;
// pad gathers hit the slice's row-0 hot line, contribute exact 0.
// Tsub nt (pure stream), Tout nt (protects slice; next step re-fetches its 2 MiB
// slice from L3 once -- part of compulsory traffic).

__global__ __launch_bounds__(256) void spmm_kernel(const int* __restrict__ cnt,
                                                   const unsigned long long* __restrict__ ev,
                                                   const unsigned short* __restrict__ Tin,
                                                   const unsigned short* __restrict__ Tsub,
                                                   unsigned short* __restrict__ Tout, int cheb) {
    int n  = blockIdx.x & 7;                     // slice -> XCD
    int vb = blockIdx.x >> 3;                    // 0..2047
    int t  = threadIdx.x;
    int g  = t >> 4;                             // vertex group 0..15
    int lq = t & 15;                             // uint lane within 64 B row
    int m  = vb * 16 + g;
    int c  = cnt[m];                             // group-uniform (broadcast load)
    int cp = (c + 7) & ~7;                       // pad to multiple of 8
    if (cp > EVROW) cp = EVROW;                  // matches scatter clamp
    const unsigned long long* evg = ev + (size_t)m * EVROW;
    const char* sb = (const char*)Tin + ((size_t)n << 21);   // slice base (2 MiB)
    unsigned int kof = (unsigned int)lq * 4u;
    float a0 = 0.f, a1 = 0.f;
    for (int j = 0; j < cp; j += 8) {
        unsigned long long ed[8];
#pragma unroll
        for (int i = 0; i < 8; ++i) ed[i] = evg[j + i];      // cached, group-uniform
        unsigned int tv[8];
#pragma unroll
        for (int i = 0; i < 8; ++i)                          // 8 outstanding 64B gathers
            tv[i] = *(const unsigned int*)(sb + (((unsigned int)ed[i]) << 6) + kof);
#pragma unroll
        for (int i = 0; i < 8; ++i) {
            float v = __builtin_bit_cast(float, (unsigned int)(ed[i] >> 32));
            a0 += v * bfl(tv[i]);
            a1 += v * bfh(tv[i]);
        }
    }
    size_t moff = ((size_t)n << 21) + (((size_t)(unsigned int)m << 6) + kof);
    if (cheb) {
        unsigned int o = __builtin_nontemporal_load(
            (const unsigned int*)((const char*)Tsub + moff));
        a0 = 2.f * a0 - bfl(o);
        a1 = 2.f * a1 - bfh(o);
    }
    __builtin_nontemporal_store(pk(a0, a1), (unsigned int*)((char*)Tout + moff));
}

// ---------------- final GEMM: out[n,m,f] = bias[f] + sum_k T_k[n][m][:] @ W_k ----------------
// MFMA 16x16x32 bf16; slice-major A -> each wave's A-read is 1 KB fully contiguous.
// grid = M/64 * 8 (n in low bits); out stores non-temporal (never re-read).

__global__ __launch_bounds__(256) void gemm_kernel(const unsigned short* __restrict__ T0,
                                                   const unsigned short* __restrict__ T1,
                                                   const unsigned short* __restrict__ T2,
                                                   const unsigned short* __restrict__ T3,
                                                   const unsigned short* __restrict__ T4,
                                                   const unsigned short* __restrict__ Wb,
                                                   const float* __restrict__ bias,
                                                   float* __restrict__ out) {
    int w = threadIdx.x >> 6;
    int l = threadIdx.x & 63;
    int n  = blockIdx.x & 7;
    int mb = blockIdx.x >> 3;
    int m0 = (mb * 4 + w) * 16;
    int lrow = l & 15;           // A's m-offset AND C's column f
    int quad = l >> 4;

    short8 bfrag[5][2];
#pragma unroll
    for (int kf = 0; kf < 10; ++kf)
        bfrag[kf >> 1][kf & 1] = *(const short8*)(Wb + ((size_t)kf * 64 + l) * 8);

    float b0 = bias[lrow];
    float b1 = bias[16 + lrow];

    const unsigned short* Ts[5] = {T0, T1, T2, T3, T4};
    size_t abase = ((size_t)n * M_VERT + (m0 + lrow)) * 32 + quad * 8;

    f32x4 c0 = {0.f, 0.f, 0.f, 0.f};
    f32x4 c1 = {0.f, 0.f, 0.f, 0.f};
#pragma unroll
    for (int k = 0; k < 5; ++k) {
        short8 a = *(const short8*)(Ts[k] + abase);
        c0 = __builtin_amdgcn_mfma_f32_16x16x32_bf16(a, bfrag[k][0], c0, 0, 0, 0);
        c1 = __builtin_amdgcn_mfma_f32_16x16x32_bf16(a, bfrag[k][1], c1, 0, 0, 0);
    }
    float* op = out + ((size_t)n * M_VERT + m0) * FILT;
#pragma unroll
    for (int r = 0; r < 4; ++r) {
        int orow = quad * 4 + r;
        __builtin_nontemporal_store(c0[r] + b0, &op[(size_t)orow * FILT + lrow]);
        __builtin_nontemporal_store(c1[r] + b1, &op[(size_t)orow * FILT + 16 + lrow]);
    }
}

// ---------------- launch ----------------

extern "C" void kernel_launch(void* const* d_in, const int* in_sizes, int n_in,
                              void* d_out, int out_size, void* d_ws, size_t ws_size,
                              hipStream_t stream) {
    const float* x    = (const float*)d_in[0];
    const float* vals = (const float*)d_in[1];
    const float* W    = (const float*)d_in[2];
    const float* bias = (const float*)d_in[3];
    const int*   rows = (const int*)d_in[4];
    const int*   cols = (const int*)d_in[5];
    float* out = (float*)d_out;

    // workspace: 5 bf16 T buffers (16 MiB each, slice-major) + fill + fixed-stride ev + Wb
    const size_t TSZ = (size_t)M_VERT * ROWLEN;
    unsigned short* T0 = (unsigned short*)d_ws;
    unsigned short* T1 = T0 + TSZ;
    unsigned short* T2 = T1 + TSZ;
    unsigned short* T3 = T2 + TSZ;
    unsigned short* T4 = T3 + TSZ;
    int*  fill = (int*)(T4 + TSZ);
    int2* ev   = (int2*)(fill + M_VERT);
    unsigned short* Wb = (unsigned short*)(ev + (size_t)M_VERT * EVROW);

    hipMemsetAsync(fill, 0, M_VERT * sizeof(int), stream);
    hipMemsetAsync(ev, 0, (size_t)M_VERT * EVROW * sizeof(int2), stream); // pads: col 0, val 0
    pack_kernel<<<M_VERT * 32 / 256, 256, 0, stream>>>(x, T0, rows, cols, vals,
                                                       fill, ev, W, Wb);

    // Chebyshev recurrence, all T_k kept (bf16); slice-major XCD-affine SpMM
    const unsigned long long* evq = (const unsigned long long*)ev;
    spmm_kernel<<<(M_VERT / 16) * 8, 256, 0, stream>>>(fill, evq, T0, T0, T1, 0);
    spmm_kernel<<<(M_VERT / 16) * 8, 256, 0, stream>>>(fill, evq, T1, T0, T2, 1);
    spmm_kernel<<<(M_VERT / 16) * 8, 256, 0, stream>>>(fill, evq, T2, T1, T3, 1);
    spmm_kernel<<<(M_VERT / 16) * 8, 256, 0, stream>>>(fill, evq, T3, T2, T4, 1);

    // single fused epilogue GEMM
    gemm_kernel<<<(M_VERT / 64) * 8, 256, 0, stream>>>(T0, T1, T2, T3, T4, Wb, bias, out);
}